// Round 5
// baseline (2765.523 us; speedup 1.0000x reference)
//
#include <hip/hip_runtime.h>
#include <math.h>

#define SS 128
#define BB 32
#define CC 16
#define DW 256
#define DC 64
#define HC 128
#define KX 384   // DW + HC
#define TT 17

typedef __attribute__((ext_vector_type(8))) short bf16x8;
typedef __attribute__((ext_vector_type(4))) float f32x4;
typedef __attribute__((ext_vector_type(4))) unsigned int u32x4;
typedef unsigned long long ull_t;

__device__ __forceinline__ float sigf(float x) { return 1.0f / (1.0f + __expf(-x)); }
__device__ __forceinline__ float tanhfast(float x) {
  float xc = fminf(fmaxf(x, -15.f), 15.f);
  float e = __expf(2.f * xc);
  return (e - 1.f) / (e + 1.f);
}
__device__ __forceinline__ unsigned short f2bf(float x) {
  unsigned int u = __float_as_uint(x);
  u += 0x7FFF + ((u >> 16) & 1);
  return (unsigned short)(u >> 16);
}
__device__ __forceinline__ bf16x8 as_bf16x8(u32x4 v) {
  union { u32x4 u; bf16x8 b; } c; c.u = v; return c.b;
}
// Agent-scope (LLC-coherent) relaxed atomics — the proven round-3 slow path.
__device__ __forceinline__ unsigned ld_u32(const unsigned* p) {
  return __hip_atomic_load(p, __ATOMIC_RELAXED, __HIP_MEMORY_SCOPE_AGENT);
}
__device__ __forceinline__ void st_u32(unsigned* p, unsigned v) {
  __hip_atomic_store(p, v, __ATOMIC_RELAXED, __HIP_MEMORY_SCOPE_AGENT);
}
__device__ __forceinline__ ull_t ld_ull(const ull_t* p) {
  return __hip_atomic_load(p, __ATOMIC_RELAXED, __HIP_MEMORY_SCOPE_AGENT);
}
__device__ __forceinline__ void st_ull(ull_t* p, ull_t v) {
  __hip_atomic_store(p, v, __ATOMIC_RELAXED, __HIP_MEMORY_SCOPE_AGENT);
}

// 8 sc0 (L2-scope) 16B loads + waitcnt fused in ONE asm block: outputs are
// defined by the block, so no use can be scheduled before the waitcnt.
#define LD8_SC0(A0,A1,A2,A3,A4,A5,A6,A7,PTR)                                  \
  asm volatile(                                                               \
    "global_load_dwordx4 %0, %8, off sc0\n\t"                                 \
    "global_load_dwordx4 %1, %8, off offset:64 sc0\n\t"                       \
    "global_load_dwordx4 %2, %8, off offset:128 sc0\n\t"                      \
    "global_load_dwordx4 %3, %8, off offset:192 sc0\n\t"                      \
    "global_load_dwordx4 %4, %8, off offset:256 sc0\n\t"                      \
    "global_load_dwordx4 %5, %8, off offset:320 sc0\n\t"                      \
    "global_load_dwordx4 %6, %8, off offset:384 sc0\n\t"                      \
    "global_load_dwordx4 %7, %8, off offset:448 sc0\n\t"                      \
    "s_waitcnt vmcnt(0)"                                                      \
    : "=v"(A0), "=v"(A1), "=v"(A2), "=v"(A3),                                 \
      "=v"(A4), "=v"(A5), "=v"(A6), "=v"(A7)                                  \
    : "v"(PTR) : "memory")

// ---------------------------------------------------------------- K0: char ih vocab table
__global__ __launch_bounds__(256) void k0_ihvocab(
    const float* __restrict__ Wce,
    const float* __restrict__ WihF, const float* __restrict__ bF,
    const float* __restrict__ WihB, const float* __restrict__ bB,
    float* __restrict__ ihv) {
  int blk = blockIdx.x;          // 0..199
  int d = blk / 100, v = blk % 100;
  const float* Wih = d ? WihB : WihF;
  const float* bb  = d ? bB   : bF;
  __shared__ float ce[DC];
  if (threadIdx.x < DC) ce[threadIdx.x] = Wce[v * DC + threadIdx.x];
  __syncthreads();
  int g = threadIdx.x;
  float acc = bb[g];
  #pragma unroll 16
  for (int k = 0; k < DC; ++k) acc += ce[k] * Wih[g * DC + k];
  ihv[(d * 100 + v) * 256 + g] = acc;
}

// ---------------------------------------------------------------- K1: char BiLSTM (per-chain, no global sync)
__global__ __launch_bounds__(256) void k1_char(
    const int* __restrict__ charidx,   // (B,S,C)
    const float* __restrict__ WhhF, const float* __restrict__ WhhB,
    const float* __restrict__ ihv,     // (2,100,256)
    float* __restrict__ x)             // (4096, 384)
{
  int blk = blockIdx.x;
  int d = blk >> 8;
  int n0 = (blk & 255) * 16;
  const float* Whh = d ? WhhB : WhhF;

  __shared__ float Wl[256 * 68];
  __shared__ float hl[16 * 68];

  for (int i = threadIdx.x; i < 256 * 64; i += 256) {
    int g = i >> 6, k = i & 63;
    Wl[g * 68 + k] = Whh[i];
  }
  __syncthreads();

  int hh = threadIdx.x & 63;
  int ng = threadIdx.x >> 6;
  float c[4] = {0.f, 0.f, 0.f, 0.f};
  float h[4] = {0.f, 0.f, 0.f, 0.f};
  int bb_[4], ss_[4];
  #pragma unroll
  for (int m = 0; m < 4; ++m) {
    int n = n0 + ng + 4 * m;
    bb_[m] = n >> 7; ss_[m] = n & 127;
  }

  for (int t = 0; t < CC; ++t) {
    int cpos = d ? (CC - 1 - t) : t;
    float acc[4][4];
    #pragma unroll
    for (int m = 0; m < 4; ++m) {
      int v = charidx[bb_[m] * (SS * CC) + ss_[m] * CC + cpos];
      const float* base = ihv + (d * 100 + v) * 256 + hh;
      acc[m][0] = base[0]; acc[m][1] = base[64]; acc[m][2] = base[128]; acc[m][3] = base[192];
    }
    if (t > 0) {
      #pragma unroll 4
      for (int k = 0; k < 64; k += 4) {
        float4 w4[4];
        #pragma unroll
        for (int q = 0; q < 4; ++q)
          w4[q] = *(const float4*)&Wl[(q * 64 + hh) * 68 + k];
        #pragma unroll
        for (int m = 0; m < 4; ++m) {
          float4 h4 = *(const float4*)&hl[(ng + 4 * m) * 68 + k];
          #pragma unroll
          for (int q = 0; q < 4; ++q)
            acc[m][q] += h4.x * w4[q].x + h4.y * w4[q].y + h4.z * w4[q].z + h4.w * w4[q].w;
        }
      }
      __syncthreads();
    }
    #pragma unroll
    for (int m = 0; m < 4; ++m) {
      float ig = sigf(acc[m][0]);
      float fg = sigf(acc[m][1]);
      float gg = tanhfast(acc[m][2]);
      float og = sigf(acc[m][3]);
      c[m] = fg * c[m] + ig * gg;
      h[m] = og * tanhfast(c[m]);
      hl[(ng + 4 * m) * 68 + hh] = h[m];
    }
    __syncthreads();
  }
  #pragma unroll
  for (int m = 0; m < 4; ++m) {
    int row = ss_[m] * BB + bb_[m];
    x[row * KX + d * 64 + hh] = h[m];
  }
}

// ---------------------------------------------------------------- K2: word embedding gather
__global__ __launch_bounds__(64) void k2_we(
    const int* __restrict__ sentence, const float* __restrict__ Wwe,
    float* __restrict__ x) {
  int row = blockIdx.x;
  int idx = sentence[row];
  const float4* src = (const float4*)(Wwe + (size_t)idx * DW);
  float4* dst = (float4*)(x + (size_t)row * KX + HC);
  dst[threadIdx.x] = src[threadIdx.x];
}

// ---------------------------------------------------------------- K3: word ih GEMM  wg[d][row][g]
__global__ __launch_bounds__(256) void k3_ihgemm(
    const float* __restrict__ x,
    const float* __restrict__ WihF, const float* __restrict__ bF,
    const float* __restrict__ WihB, const float* __restrict__ bB,
    float* __restrict__ wg) {
  int n0 = blockIdx.x * 128;
  int m0 = blockIdx.y * 128;
  int d  = n0 >> 10;
  int gb = n0 & 1023;
  const float* Wih  = d ? WihB : WihF;
  const float* bias = d ? bB   : bF;

  __shared__ float At[32][132];
  __shared__ float Bt[32][132];

  int tid = threadIdx.x;
  int half = tid & 1, r = tid >> 1;
  int tm = tid & 15, tn = tid >> 4;
  float acc[8][8] = {};

  for (int k0 = 0; k0 < KX; k0 += 32) {
    __syncthreads();
    {
      const float4* srcA = (const float4*)(x + (size_t)(m0 + r) * KX + k0 + half * 16);
      const float4* srcB = (const float4*)(Wih + (size_t)(gb + r) * KX + k0 + half * 16);
      #pragma unroll
      for (int q = 0; q < 4; ++q) {
        float4 v = srcA[q];
        int kk = half * 16 + q * 4;
        At[kk + 0][r] = v.x; At[kk + 1][r] = v.y; At[kk + 2][r] = v.z; At[kk + 3][r] = v.w;
      }
      #pragma unroll
      for (int q = 0; q < 4; ++q) {
        float4 v = srcB[q];
        int kk = half * 16 + q * 4;
        Bt[kk + 0][r] = v.x; Bt[kk + 1][r] = v.y; Bt[kk + 2][r] = v.z; Bt[kk + 3][r] = v.w;
      }
    }
    __syncthreads();
    #pragma unroll 8
    for (int k = 0; k < 32; ++k) {
      float4 a0 = *(const float4*)&At[k][tm * 8];
      float4 a1 = *(const float4*)&At[k][tm * 8 + 4];
      float4 b0 = *(const float4*)&Bt[k][tn * 8];
      float4 b1 = *(const float4*)&Bt[k][tn * 8 + 4];
      float av[8] = {a0.x, a0.y, a0.z, a0.w, a1.x, a1.y, a1.z, a1.w};
      float bv[8] = {b0.x, b0.y, b0.z, b0.w, b1.x, b1.y, b1.z, b1.w};
      #pragma unroll
      for (int i = 0; i < 8; ++i)
        #pragma unroll
        for (int jq = 0; jq < 8; ++jq)
          acc[i][jq] += av[i] * bv[jq];
    }
  }
  float bv8[8];
  #pragma unroll
  for (int jq = 0; jq < 8; ++jq) bv8[jq] = bias[gb + tn * 8 + jq];
  #pragma unroll
  for (int i = 0; i < 8; ++i) {
    int m = m0 + tm * 8 + i;
    float* dst = wg + ((size_t)(d * 4096 + m)) * 1024 + gb + tn * 8;
    float4 v0 = {acc[i][0] + bv8[0], acc[i][1] + bv8[1], acc[i][2] + bv8[2], acc[i][3] + bv8[3]};
    float4 v1 = {acc[i][4] + bv8[4], acc[i][5] + bv8[5], acc[i][6] + bv8[6], acc[i][7] + bv8[7]};
    *(float4*)dst = v0; *(float4*)(dst + 4) = v1;
  }
}

// ---------------------------------------------------------------- K4: word BiLSTM recurrence
// 256 WGs x 64 thr self-organize by XCC_ID; first XCD to collect 32 WGs runs
// the recurrence (16 waves/dir) entirely inside its own L2 (sc0 protocol).
// Producers ALWAYS dual-publish (sc0 fast copy + LLC slow copy); consumers
// use a capped sc0 poll and fall back (sticky) to the proven LLC protocol.
// Every wait is bounded -> kernel cannot hang.
__global__ __launch_bounds__(64, 1) void k4_word(
    const float* __restrict__ WhhF, const float* __restrict__ WhhB,
    const float* __restrict__ wg,           // (2,4096,1024) f32
    float* __restrict__ outh,               // (4096,512) f32
    unsigned short* __restrict__ hbuf,      // fast copy: (2 dir, 2 par, 32 b, 256 k) bf16
    unsigned short* __restrict__ hbuf2,     // slow copy: same layout
    unsigned int* __restrict__ ctrl) {      // [0..7] cnt, [8] winner, ftags @+256, stags @+1024 dwords
  const int l = threadIdx.x;                // 0..63

  // ---- election (bounded) ----
  unsigned xcd;
  asm volatile("s_getreg_b32 %0, hwreg(HW_REG_XCC_ID)" : "=s"(xcd));
  xcd &= 7u;                                 // 8 buckets: pigeonhole over 256 WGs
  unsigned ticket = 0xffffffffu;
  if (l == 0) {
    ticket = atomicAdd(&ctrl[xcd], 1u);      // device-scope, LLC
    if (ticket == 31u) atomicCAS(&ctrl[8], 0u, xcd + 1u);
  }
  ticket = (unsigned)__shfl((int)ticket, 0);
  unsigned win = 0u;
  for (int it = 0; it < (1 << 20); ++it) {
    win = ld_u32(&ctrl[8]);
    if (win != 0u) break;
    __builtin_amdgcn_s_sleep(2);
  }
  if (win == 0u || xcd + 1u != win || ticket >= 32u) return;

  const int d = (int)(ticket >> 4), widx = (int)(ticket & 15u);
  const int l15 = l & 15, q4 = l >> 4;
  const int j0w = widx * 16;
  const float* __restrict__ Whh = d ? WhhB : WhhF;
  unsigned short* hb_d  = hbuf  + d * 16384;   // 2 parities * 8192
  unsigned short* hb2_d = hbuf2 + d * 16384;
  unsigned int* ftag = ctrl + 256  + d * 256;  // fast tags (sc0), stride 16 dwords
  unsigned int* stag = ctrl + 1024 + d * 256;  // slow tags (LLC)
  unsigned int* myftag = ftag + widx * 16;
  unsigned int* mystag = stag + widx * 16;
  const unsigned int* pollf = ftag + l15 * 16;
  const unsigned int* polls = stag + l15 * 16;

  __shared__ unsigned short hl[32 * 24];       // transpose tile, row stride 48B

  // ---- Whh B-fragments resident: lane holds B[k=ks*32+q4*8+j][n=l15]
  bf16x8 Bf[4][8];
  #pragma unroll
  for (int q = 0; q < 4; ++q) {
    const float* wr = Whh + (size_t)(q * 256 + j0w + l15) * 256 + q4 * 8;
    #pragma unroll
    for (int ks = 0; ks < 8; ++ks) {
      float4 lo = *(const float4*)(wr + ks * 32);
      float4 hi = *(const float4*)(wr + ks * 32 + 4);
      bf16x8 f;
      f[0] = (short)f2bf(lo.x); f[1] = (short)f2bf(lo.y);
      f[2] = (short)f2bf(lo.z); f[3] = (short)f2bf(lo.w);
      f[4] = (short)f2bf(hi.x); f[5] = (short)f2bf(hi.y);
      f[6] = (short)f2bf(hi.z); f[7] = (short)f2bf(hi.w);
      Bf[q][ks] = f;
    }
  }

  float cst[8];
  #pragma unroll
  for (int i = 0; i < 8; ++i) cst[i] = 0.f;

  const int rb = l >> 1;          // transpose-read row (batch) 0..31
  const int rh = l & 1;           // transpose-read half-chunk
  int slow = 0;                   // sticky fallback flag (wave-uniform)

  for (int t = 0; t < SS; ++t) {
    const int s = d ? (SS - 1 - t) : t;

    // ---- ih gates into MFMA C-layout (plain loads; overlap the poll)
    f32x4 acc[4][2];
    const float* wgs = wg + ((size_t)d * 4096 + (size_t)s * 32) * 1024 + j0w + l15;
    #pragma unroll
    for (int q = 0; q < 4; ++q)
      #pragma unroll
      for (int mt = 0; mt < 2; ++mt)
        #pragma unroll
        for (int r = 0; r < 4; ++r)
          acc[q][mt][r] = wgs[(size_t)(q4 * 4 + r + mt * 16) * 1024 + q * 256];

    if (t > 0) {
      // ---- wait for the 16 producers of this direction
      if (!slow) {
        int ok = 0;
        for (int it = 0; it < 16384; ++it) {
          unsigned tg;
          asm volatile("global_load_dword %0, %1, off sc0\n\ts_waitcnt vmcnt(0)"
                       : "=v"(tg) : "v"((const void*)pollf) : "memory");
          if (__all((int)(tg >= (unsigned)t))) { ok = 1; break; }
        }
        if (!ok) slow = 1;                    // sticky: switch to LLC protocol
      }
      if (slow) {
        for (int it = 0; it < (1 << 20); ++it) {
          unsigned tg = ld_u32(polls);
          if (__all((int)(tg >= (unsigned)t))) break;
          __builtin_amdgcn_s_sleep(1);
        }
      }

      // ---- A-fragments of h_{t-1}
      bf16x8 Af[2][8];
      if (!slow) {
        #pragma unroll
        for (int mt = 0; mt < 2; ++mt) {
          const unsigned short* hp =
              hb_d + ((t - 1) & 1) * 8192 + (size_t)(l15 + mt * 16) * 256 + q4 * 8;
          u32x4 a0, a1, a2, a3, a4, a5, a6, a7;
          LD8_SC0(a0, a1, a2, a3, a4, a5, a6, a7, (const void*)hp);
          Af[mt][0] = as_bf16x8(a0); Af[mt][1] = as_bf16x8(a1);
          Af[mt][2] = as_bf16x8(a2); Af[mt][3] = as_bf16x8(a3);
          Af[mt][4] = as_bf16x8(a4); Af[mt][5] = as_bf16x8(a5);
          Af[mt][6] = as_bf16x8(a6); Af[mt][7] = as_bf16x8(a7);
        }
      } else {
        const unsigned short* hp2 = hb2_d + ((t - 1) & 1) * 8192 + q4 * 8;
        #pragma unroll
        for (int mt = 0; mt < 2; ++mt)
          #pragma unroll
          for (int ks = 0; ks < 8; ++ks) {
            const ull_t* p = (const ull_t*)(hp2 + (size_t)(l15 + mt * 16) * 256 + ks * 32);
            union { ull_t u[2]; bf16x8 v; } cvt;
            cvt.u[0] = ld_ull(p);
            cvt.u[1] = ld_ull(p + 1);
            Af[mt][ks] = cvt.v;
          }
      }

      #pragma unroll
      for (int q = 0; q < 4; ++q)
        #pragma unroll
        for (int mt = 0; mt < 2; ++mt) {
          f32x4 c = acc[q][mt];
          #pragma unroll
          for (int ks = 0; ks < 8; ++ks)
            c = __builtin_amdgcn_mfma_f32_16x16x32_bf16(Af[mt][ks], Bf[q][ks], c, 0, 0, 0);
          acc[q][mt] = c;
        }
    }

    // ---- activations; lane owns (b = q4*4+r+mt*16, col = j0w+l15)
    float hv[8];
    #pragma unroll
    for (int mt = 0; mt < 2; ++mt)
      #pragma unroll
      for (int r = 0; r < 4; ++r) {
        int ix = mt * 4 + r;
        float ig = sigf(acc[0][mt][r]);
        float fg = sigf(acc[1][mt][r]);
        float gg = tanhfast(acc[2][mt][r]);
        float og = sigf(acc[3][mt][r]);
        float c2 = fg * cst[ix] + ig * gg;
        cst[ix] = c2;
        hv[ix] = og * tanhfast(c2);
      }

    // ---- wave-local LDS transpose → dual publish (sc0 fast + LLC slow)
    #pragma unroll
    for (int mt = 0; mt < 2; ++mt)
      #pragma unroll
      for (int r = 0; r < 4; ++r)
        hl[(q4 * 4 + r + mt * 16) * 24 + l15] = f2bf(hv[mt * 4 + r]);
    u32x4 pdata = *(const u32x4*)&hl[rb * 24 + rh * 8];   // 16B aligned (48B rows)
    {
      void* dstf = (void*)(hb_d + (t & 1) * 8192 + (size_t)rb * 256 + j0w + rh * 8);
      asm volatile("global_store_dwordx4 %0, %1, off sc0" :: "v"(dstf), "v"(pdata) : "memory");
      ull_t* dsts = (ull_t*)(hb2_d + (t & 1) * 8192 + (size_t)rb * 256 + j0w + rh * 8);
      union { u32x4 u; ull_t q[2]; } pu; pu.u = pdata;
      st_ull(dsts, pu.q[0]);
      st_ull(dsts + 1, pu.q[1]);
    }
    asm volatile("s_waitcnt vmcnt(0)" ::: "memory");       // drain both publishes
    if (l == 0) {
      asm volatile("global_store_dword %0, %1, off sc0"
                   :: "v"((void*)myftag), "v"((unsigned)(t + 1)) : "memory");
      st_u32(mystag, (unsigned)(t + 1));
    }

    // ---- outh (plain stores; drained by next step's waitcnt)
    float* op = outh + (size_t)(s * 32) * 512 + d * 256 + j0w + l15;
    #pragma unroll
    for (int mt = 0; mt < 2; ++mt)
      #pragma unroll
      for (int r = 0; r < 4; ++r)
        op[(size_t)(q4 * 4 + r + mt * 16) * 512] = hv[mt * 4 + r];
  }
}

// ---------------------------------------------------------------- K5: emit GEMM (3 rows/block)
__global__ __launch_bounds__(64) void k5_emit(
    const float* __restrict__ outh, const float* __restrict__ eW,
    const float* __restrict__ eb, float* __restrict__ em) {
  int t = threadIdx.x;
  int rr = t / 17, tt = t % 17;
  int row = blockIdx.x * 3 + rr;
  if (rr < 3 && row < 4096) {
    const float4* o4 = (const float4*)(outh + (size_t)row * 512);
    const float4* w4 = (const float4*)(eW + (size_t)tt * 512);
    float acc = 0.f;
    #pragma unroll 16
    for (int k = 0; k < 128; ++k) {
      float4 a = o4[k], bq = w4[k];
      acc += a.x * bq.x + a.y * bq.y + a.z * bq.z + a.w * bq.w;
    }
    em[row * TT + tt] = acc + eb[tt];
  }
}

// ---------------------------------------------------------------- K6: CRF NLL (32 independent batches)
__global__ __launch_bounds__(64) void k6_crf(
    const int* __restrict__ sentence, const int* __restrict__ tags,
    const float* __restrict__ em, const float* __restrict__ trans,
    const float* __restrict__ startv, const float* __restrict__ endv,
    float* __restrict__ outp) {
  int b = blockIdx.x;
  int j = threadIdx.x;
  __shared__ float ash[TT];
  __shared__ float red[TT];
  float tc[TT];
  float alpha = 0.f;
  if (j < TT) {
    #pragma unroll
    for (int i = 0; i < TT; ++i) tc[i] = trans[i * TT + j];
    alpha = startv[j] + em[(0 * BB + b) * TT + j];
  }
  for (int s = 1; s < SS; ++s) {
    if (j < TT) ash[j] = alpha;
    __syncthreads();
    int m = (sentence[s * BB + b] != 1) ? 1 : 0;
    if (j < TT) {
      float mx = -1e30f;
      #pragma unroll
      for (int i = 0; i < TT; ++i) mx = fmaxf(mx, ash[i] + tc[i]);
      float sum = 0.f;
      #pragma unroll
      for (int i = 0; i < TT; ++i) sum += __expf(ash[i] + tc[i] - mx);
      float nxt = mx + __logf(sum) + em[(s * BB + b) * TT + j];
      if (m) alpha = nxt;
    }
    __syncthreads();
  }
  if (j < TT) red[j] = alpha + endv[j];
  __syncthreads();
  if (j == 0) {
    float mx = -1e30f;
    for (int i = 0; i < TT; ++i) mx = fmaxf(mx, red[i]);
    float sum = 0.f;
    for (int i = 0; i < TT; ++i) sum += __expf(red[i] - mx);
    float den = mx + __logf(sum);
    int prev = tags[0 * BB + b];
    float num = startv[prev] + em[(0 * BB + b) * TT + prev];
    for (int s = 1; s < SS; ++s) {
      int tg = tags[s * BB + b];
      if (sentence[s * BB + b] != 1) {
        num += trans[prev * TT + tg] + em[(s * BB + b) * TT + tg];
        prev = tg;
      }
    }
    num += endv[prev];
    atomicAdd(outp, den - num);
  }
}

// ---------------------------------------------------------------- launcher
extern "C" void kernel_launch(void* const* d_in, const int* in_sizes, int n_in,
                              void* d_out, int out_size, void* d_ws, size_t ws_size,
                              hipStream_t stream) {
  (void)in_sizes; (void)n_in; (void)out_size; (void)ws_size;
  const int*   sentence = (const int*)d_in[0];
  const int*   charidx  = (const int*)d_in[1];
  const int*   tags     = (const int*)d_in[2];
  const float* Wwe   = (const float*)d_in[3];
  const float* Wce   = (const float*)d_in[4];
  const float* cWihF = (const float*)d_in[5];
  const float* cWhhF = (const float*)d_in[6];
  const float* cbF   = (const float*)d_in[7];
  const float* wWihF = (const float*)d_in[8];
  const float* wWhhF = (const float*)d_in[9];
  const float* wbF   = (const float*)d_in[10];
  const float* cWihB = (const float*)d_in[11];
  const float* cWhhB = (const float*)d_in[12];
  const float* cbB   = (const float*)d_in[13];
  const float* wWihB = (const float*)d_in[14];
  const float* wWhhB = (const float*)d_in[15];
  const float* wbB   = (const float*)d_in[16];
  const float* eW    = (const float*)d_in[17];
  const float* eb    = (const float*)d_in[18];
  const float* trans = (const float*)d_in[19];
  const float* startv= (const float*)d_in[20];
  const float* endv  = (const float*)d_in[21];

  char* ws = (char*)d_ws;
  unsigned int*   ctrl  = (unsigned int*)(ws + 0);           //    8192 B
  float*          ihv   = (float*)(ws + 8192);               //  204800 B
  float*          x     = (float*)(ws + 212992);             // 6291456 B
  float*          wg    = (float*)(ws + 6504448);            // 33554432 B
  unsigned short* hbuf  = (unsigned short*)(ws + 40058880);  //   65536 B
  unsigned short* hbuf2 = (unsigned short*)(ws + 40124416);  //   65536 B
  float*          outh  = (float*)(ws + 40189952);           // 8388608 B
  float*          em    = (float*)(ws + 48578560);           //  278528 B
  // total ws usage: 48,857,088 B

  hipMemsetAsync(ctrl, 0, 8192, stream);
  hipMemsetAsync(d_out, 0, sizeof(float), stream);

  k0_ihvocab<<<200, 256, 0, stream>>>(Wce, cWihF, cbF, cWihB, cbB, ihv);
  k1_char<<<512, 256, 0, stream>>>(charidx, cWhhF, cWhhB, ihv, x);
  k2_we<<<4096, 64, 0, stream>>>(sentence, Wwe, x);
  k3_ihgemm<<<dim3(16, 32), 256, 0, stream>>>(x, wWihF, wbF, wWihB, wbB, wg);
  k4_word<<<256, 64, 0, stream>>>(wWhhF, wWhhB, wg, outh, hbuf, hbuf2, ctrl);
  k5_emit<<<1366, 64, 0, stream>>>(outh, eW, eb, em);
  k6_crf<<<32, 64, 0, stream>>>(sentence, tags, em, trans, startv, endv, (float*)d_out);
}